// Round 11
// baseline (204.228 us; speedup 1.0000x reference)
//
#include <hip/hip_runtime.h>
#include <math.h>

#define T_ 32
#define B_ 16
#define V_ 30000
#define V4 7500
#define D_ 300
#define DQKV_ 150
#define KSTR 152              // KC row stride (pad 150 -> 152 floats, 16B aligned)
#define K_ 10
#define G_ 32
#define N_ 320                // K*G
#define S_ 25000
#define S4 6250
#define GRW 64                // gemm rows per block (1 per lane)
#define APAD 301              // LDS row pitch: 13*lane mod 32 -> 2-way (free)
#define NBK3 391              // ceil(25000/64)
#define NBQ3 8                // 512/64
#define NTG 512               // gemm threads: 8 waves x 19 cols
#define NTS 1024              // scan threads
#define NTA 512               // attn threads
#define LCAP 4096             // candidate list capacity (expect ~680 for N(0,1))
#define UTH 0xC0000000u       // u-map(2.0f): accept x >= 2.0

__device__ __forceinline__ unsigned umap(float f) {
    unsigned b = __float_as_uint(f);
    unsigned mask = (unsigned)(((int)b) >> 31);      // 0xFFFFFFFF if negative
    return b ^ (mask | 0x80000000u);                 // ascending uint == ascending float
}
__device__ __forceinline__ bool better_u(unsigned au, int ai, unsigned bu, int bi) {
    return (au > bu) || (au == bu && ai < bi);       // higher val, ties -> lower idx
}

// ======= Kernel 1: KC = SC@Wk, Q = lc@Wq — row-per-lane, scalar B-operand ====
// 8 waves/block, wave w owns cols [w*19, w*19+19) (last group clamped).
// B loads wave-uniform -> SGPR s_load; A from LDS (2-way banks = free);
// d-loop unrolled x4: 4 batched ds_reads + 76 W-floats hoisted per group.
__global__ __launch_bounds__(NTG, 2) void gemm_kernel(
    const float* __restrict__ SC, const float* __restrict__ lc,
    const float* __restrict__ Wk, const float* __restrict__ Wq,
    float* __restrict__ KC, float* __restrict__ Qws)
{
    __shared__ float at[GRW * APAD];                 // 77.06 KB -> 2 blocks/CU
    const int b = blockIdx.x;
    const float* A; const float* Bw; float* O; int row0, M;
    if (b < NBK3) { A = SC; Bw = Wk; O = KC;  row0 = b * GRW;          M = S_; }
    else          { A = lc; Bw = Wq; O = Qws; row0 = (b - NBK3) * GRW; M = T_ * B_; }
    const int nr = (M - row0 < GRW) ? (M - row0) : GRW;

    // stage A tile: coalesced global float4 -> 4x b32 LDS
    {
        const float4* a4 = (const float4*)(A + (size_t)row0 * D_);
        for (int i = threadIdx.x; i < nr * (D_ / 4); i += NTG) {
            int r = i / (D_ / 4), q = i - r * (D_ / 4);
            float4 v = a4[i];
            float* dst = at + r * APAD + q * 4;
            dst[0] = v.x; dst[1] = v.y; dst[2] = v.z; dst[3] = v.w;
        }
    }
    __syncthreads();

    const int lane = threadIdx.x & 63;               // = row within tile
    const int wv   = threadIdx.x >> 6;               // 0..7
    const int c0   = __builtin_amdgcn_readfirstlane(wv * 19);   // 0,19,...,133

    // clamped column offsets (SGPR, hoisted; cols 150/151 read col 0, never stored)
    int colofs[19];
    #pragma unroll
    for (int cc = 0; cc < 19; ++cc) {
        int col = c0 + cc;
        colofs[cc] = (col < DQKV_) ? col : 0;
    }

    float acc[19];
    #pragma unroll
    for (int cc = 0; cc < 19; ++cc) acc[cc] = 0.f;

    const float* arow = at + lane * APAD;
    for (int d = 0; d < D_; d += 4) {
        float a0 = arow[d + 0];                      // 4 independent ds_read_b32
        float a1 = arow[d + 1];
        float a2 = arow[d + 2];
        float a3 = arow[d + 3];
        const float* w0 = Bw + (size_t)(d + 0) * DQKV_;   // wave-uniform -> s_load
        const float* w1 = Bw + (size_t)(d + 1) * DQKV_;
        const float* w2 = Bw + (size_t)(d + 2) * DQKV_;
        const float* w3 = Bw + (size_t)(d + 3) * DQKV_;
        #pragma unroll
        for (int cc = 0; cc < 19; ++cc) {
            acc[cc] += a0 * w0[colofs[cc]];
            acc[cc] += a1 * w1[colofs[cc]];
            acc[cc] += a2 * w2[colofs[cc]];
            acc[cc] += a3 * w3[colofs[cc]];
        }
    }

    if (lane < nr) {
        float* orow = O + (size_t)(row0 + lane) * KSTR;
        #pragma unroll
        for (int cc = 0; cc < 19; ++cc) {
            int col = c0 + cc;
            if (col < DQKV_) orow[col] = acc[cc];
        }
    }
    // zero the 2-float row pad (attn reads rows as 38 float4)
    for (int i = threadIdx.x; i < nr * 2; i += NTG)
        O[(size_t)(row0 + (i >> 1)) * KSTR + DQKV_ + (i & 1)] = 0.f;
}

// ===== Kernel 2: fill + threshold-collect + exact top-10 select per row =====
__global__ __launch_bounds__(NTS, 2) void scan_kernel(
    const float* __restrict__ pred, float* __restrict__ out,
    int* __restrict__ wstop)
{
    const int row = blockIdx.x, tid = threadIdx.x;
    const int lane = tid & 63, wave = tid >> 6;
    __shared__ unsigned lu[LCAP];          // 16 KB candidate u-keys
    __shared__ int      li[LCAP];          // 16 KB candidate indices
    __shared__ int      cnt;

    if (tid == 0) cnt = 0;
    __syncthreads();

    // fill output row with log(1e-8)
    const float FILL = -18.420680743952367f;
    {
        float4 f4 = make_float4(FILL, FILL, FILL, FILL);
        float4* o4 = (float4*)(out + (size_t)row * S_);
        #pragma unroll
        for (int k = 0; k < 7; ++k) { int i = tid + k * NTS; if (i < S4) o4[i] = f4; }
    }

    // stream row: collect candidates with x >= 2.0 (u >= UTH); pure streaming
    {
        const float4* p4 = (const float4*)(pred + (size_t)row * V_);
        #pragma unroll
        for (int k = 0; k < 8; ++k) {
            int i = tid + k * NTS;
            if (i < V4) {
                float4 v = p4[i];
                unsigned u0 = umap(v.x), u1 = umap(v.y), u2 = umap(v.z), u3 = umap(v.w);
                int base = i * 4;
                if (u0 >= UTH) { int p = atomicAdd(&cnt, 1); if (p < LCAP) { lu[p] = u0; li[p] = base; } }
                if (u1 >= UTH) { int p = atomicAdd(&cnt, 1); if (p < LCAP) { lu[p] = u1; li[p] = base + 1; } }
                if (u2 >= UTH) { int p = atomicAdd(&cnt, 1); if (p < LCAP) { lu[p] = u2; li[p] = base + 2; } }
                if (u3 >= UTH) { int p = atomicAdd(&cnt, 1); if (p < LCAP) { lu[p] = u3; li[p] = base + 3; } }
            }
        }
    }
    __syncthreads();
    const int c = cnt;

    if (c >= K_ && c <= LCAP) {
        // main path: wave 0 selects exact top-10 from c candidates
        if (wave == 0) {
            for (int p = 0; p < K_; ++p) {
                unsigned bu = 0; int bi = 0x7fffffff;
                for (int s = lane; s < c; s += 64) {
                    unsigned uu = lu[s]; int ii = li[s];
                    if (better_u(uu, ii, bu, bi)) { bu = uu; bi = ii; }
                }
                #pragma unroll
                for (int off = 32; off; off >>= 1) {
                    unsigned ou = __shfl_xor(bu, off, 64);
                    int      oi = __shfl_xor(bi, off, 64);
                    if (better_u(ou, oi, bu, bi)) { bu = ou; bi = oi; }
                }
                if (lane == 0) wstop[row * K_ + p] = bi;
                // remove winner (unique by idx)
                for (int s = lane; s < c; s += 64)
                    if (li[s] == bi && lu[s] == bu) lu[s] = 0;
            }
        }
    } else {
        // exact fallback (never triggers for N(0,1) input): wave 0 re-scans row
        if (wave == 0) {
            unsigned tu[K_]; int tix[K_];
            #pragma unroll
            for (int s = 0; s < K_; ++s) { tu[s] = 0; tix[s] = 0x7fffffff; }
            const float* prow = pred + (size_t)row * V_;
            for (int i = lane; i < V_; i += 64) {
                unsigned u = umap(prow[i]);
                if (better_u(u, i, tu[K_-1], tix[K_-1])) {
                    tu[K_-1] = u; tix[K_-1] = i;
                    #pragma unroll
                    for (int s = K_-1; s > 0; --s)
                        if (better_u(tu[s], tix[s], tu[s-1], tix[s-1])) {
                            unsigned a = tu[s]; tu[s] = tu[s-1]; tu[s-1] = a;
                            int b2 = tix[s]; tix[s] = tix[s-1]; tix[s-1] = b2;
                        }
                }
            }
            for (int p = 0; p < K_; ++p) {
                unsigned bu = tu[0]; int bi = tix[0];
                #pragma unroll
                for (int s = 1; s < K_; ++s)
                    if (better_u(tu[s], tix[s], bu, bi)) { bu = tu[s]; bi = tix[s]; }
                #pragma unroll
                for (int off = 32; off; off >>= 1) {
                    unsigned ou = __shfl_xor(bu, off, 64);
                    int      oi = __shfl_xor(bi, off, 64);
                    if (better_u(ou, oi, bu, bi)) { bu = ou; bi = oi; }
                }
                if (lane == 0) wstop[row * K_ + p] = bi;
                #pragma unroll
                for (int s = 0; s < K_; ++s)
                    if (tix[s] == bi) tu[s] = 0;
            }
        }
    }
}

// ============ Kernel 3: neighbours + logits + softmax + scatter ==============
__global__ __launch_bounds__(NTA) void attn_kernel(
    const float* __restrict__ KC, const float* __restrict__ Qws,
    const int* __restrict__ nbt, const int* __restrict__ wstop,
    float* __restrict__ out)
{
    const int row = blockIdx.x, tid = threadIdx.x;
    const int lane = tid & 63, wave = tid >> 6;
    __shared__ int   topg[K_];
    __shared__ __align__(16) float qsh[KSTR];
    __shared__ int   nidx[N_];
    __shared__ float lg[N_];
    __shared__ int   kills[N_];
    __shared__ float redA[8], redB[8];
    float* outrow = out + (size_t)row * S_;

    if (tid < K_) topg[tid] = wstop[row * K_ + tid];
    else if (tid >= 64 && tid < 64 + KSTR / 4)        // 38 threads: q row as float4
        ((float4*)qsh)[tid - 64] = ((const float4*)(Qws + (size_t)row * KSTR))[tid - 64];
    else if (tid >= 192)                              // 320 threads: zero kill flags
        kills[tid - 192] = 0;
    __syncthreads();                                   // BAR1

    if (tid < N_) nidx[tid] = nbt[topg[tid >> 5] * G_ + (tid & 31)];
    __syncthreads();                                   // BAR2

    // logits[n] = q . KC[nidx[n]] * ISC : 2 lanes per dot, 19 float4 each
    const float ISC = 0.08164965809277260327f;   // 1/sqrt(150)
    const float4* q4 = (const float4*)qsh;
    for (int s = tid; s < 2 * N_; s += NTA) {
        int n = s >> 1, h = s & 1;
        const float4* kc4 = (const float4*)(KC + (size_t)nidx[n] * KSTR) + h * 19;
        const float4* qq4 = q4 + h * 19;
        float acc = 0.f;
        #pragma unroll
        for (int cc = 0; cc < 19; ++cc) {
            float4 x = kc4[cc];
            float4 bq = qq4[cc];
            acc += x.x * bq.x + x.y * bq.y + x.z * bq.z + x.w * bq.w;
        }
        acc += __shfl_xor(acc, 1, 64);
        if (h == 0) lg[n] = acc * ISC;
    }
    __syncthreads();                                   // BAR3

    float v = (tid < N_) ? lg[tid] : -INFINITY;
    float m = v;
    #pragma unroll
    for (int off = 32; off; off >>= 1) m = fmaxf(m, __shfl_xor(m, off, 64));
    if (lane == 0) redA[wave] = m;
    __syncthreads();                                   // BAR4
    m = redA[0];
    #pragma unroll
    for (int w = 1; w < 8; ++w) m = fmaxf(m, redA[w]);

    float ss = (tid < N_) ? expf(v - m) : 0.f;
    #pragma unroll
    for (int off = 32; off; off >>= 1) ss += __shfl_xor(ss, off, 64);
    if (lane == 0) redB[wave] = ss;
    __syncthreads();                                   // BAR5
    float tot = redB[0];
    #pragma unroll
    for (int w = 1; w < 8; ++w) tot += redB[w];
    float lsum = logf(tot);

    // last-write-wins duplicate detection: 1280 chunk-scans of width 80
    for (int s = tid; s < 4 * N_; s += NTA) {
        int n = s >> 2, cix = s & 3;
        int sidx = nidx[n];
        int clo = cix * 80;
        int lo = (n + 1 > clo) ? n + 1 : clo;
        int hi = clo + 80;
        bool mt = false;
        #pragma unroll 4
        for (int n2 = lo; n2 < hi; ++n2) mt |= (nidx[n2] == sidx);
        if (mt) kills[n] = 1;
    }
    __syncthreads();                                   // BAR6

    if (tid < N_ && !kills[tid]) outrow[nidx[tid]] = (v - m) - lsum;
}

// ================= Fallback: fused single kernel (needs no ws) ===============
#define NWS 16
__device__ __forceinline__ bool better(float av, int ai, float bv, int bi) {
    return (av > bv) || (av == bv && ai < bi);
}
__global__ __launch_bounds__(NTS, 4) void selfatt_fused(
    const float* __restrict__ pred, const float* __restrict__ lc,
    const float* __restrict__ SC, const float* __restrict__ Wq,
    const float* __restrict__ Wk, const int* __restrict__ nbt,
    float* __restrict__ out)
{
    const int row = blockIdx.x, tid = threadIdx.x;
    const int lane = tid & 63, wave = tid >> 6;
    __shared__ float wcv[NWS * K_];
    __shared__ int   wci[NWS * K_];
    __shared__ int   topg[K_];
    __shared__ float lcs[D_];
    __shared__ float qs[DQKV_];
    __shared__ __align__(16) float qks[D_];
    __shared__ int   nidx[N_];
    __shared__ float lg[N_];
    __shared__ int   kills[N_];
    __shared__ float redA[NWS], redB[NWS];
    float* outrow = out + (size_t)row * S_;
    const float FILL = -18.420680743952367f;
    {
        float4 f4 = make_float4(FILL, FILL, FILL, FILL);
        float4* o4 = (float4*)outrow;
        #pragma unroll
        for (int k = 0; k < 7; ++k) { int i = tid + k * NTS; if (i < S4) o4[i] = f4; }
    }
    float tv[K_]; int ti[K_];
    #pragma unroll
    for (int s = 0; s < K_; ++s) { tv[s] = -INFINITY; ti[s] = 0x7fffffff; }
    {
        const float4* p4 = (const float4*)(pred + (size_t)row * V_);
        const float4 NEG = make_float4(-INFINITY, -INFINITY, -INFINITY, -INFINITY);
        float4 a[8]; int ib[8];
        #pragma unroll
        for (int u = 0; u < 8; ++u) {
            int i = tid + u * NTS;
            a[u]  = (i < V4) ? p4[i] : NEG;
            ib[u] = (i < V4) ? i * 4 : 0x7ffffff0;
        }
        #pragma unroll
        for (int u = 0; u < 8; ++u) {
            float x = a[u].x, y = a[u].y, z = a[u].z, w = a[u].w;
            float m4 = fmaxf(fmaxf(x, y), fmaxf(z, w));
            if (!(m4 < tv[K_-1])) {
                float vals[4] = {x, y, z, w};
                #pragma unroll
                for (int cc = 0; cc < 4; ++cc) {
                    float val = vals[cc];
                    int   idx = ib[u] + cc;
                    if (better(val, idx, tv[K_-1], ti[K_-1])) {
                        tv[K_-1] = val; ti[K_-1] = idx;
                        #pragma unroll
                        for (int s = K_-1; s > 0; --s) {
                            if (better(tv[s], ti[s], tv[s-1], ti[s-1])) {
                                float fx = tv[s]; tv[s] = tv[s-1]; tv[s-1] = fx;
                                int   iy = ti[s]; ti[s] = ti[s-1]; ti[s-1] = iy;
                            }
                        }
                    }
                }
            }
        }
    }
    for (int p = 0; p < K_; ++p) {
        float bv = tv[0]; int bi = ti[0];
        #pragma unroll
        for (int s = 1; s < K_; ++s)
            if (better(tv[s], ti[s], bv, bi)) { bv = tv[s]; bi = ti[s]; }
        #pragma unroll
        for (int off = 32; off; off >>= 1) {
            float ov = __shfl_xor(bv, off, 64);
            int   oi = __shfl_xor(bi, off, 64);
            if (better(ov, oi, bv, bi)) { bv = ov; bi = oi; }
        }
        if (lane == 0) { wcv[wave * K_ + p] = bv; wci[wave * K_ + p] = bi; }
        #pragma unroll
        for (int s = 0; s < K_; ++s)
            if (ti[s] == bi) tv[s] = -INFINITY;
    }
    __syncthreads();
    if (wave == 0) {
        float c0v = wcv[lane],      c1v = wcv[64 + lane];
        int   c0i = wci[lane],      c1i = wci[64 + lane];
        float c2v = (lane < 32) ? wcv[128 + lane] : -INFINITY;
        int   c2i = (lane < 32) ? wci[128 + lane] : 0x7fffffff;
        for (int p = 0; p < K_; ++p) {
            float bv = c0v; int bi = c0i;
            if (better(c1v, c1i, bv, bi)) { bv = c1v; bi = c1i; }
            if (better(c2v, c2i, bv, bi)) { bv = c2v; bi = c2i; }
            #pragma unroll
            for (int off = 32; off; off >>= 1) {
                float ov = __shfl_xor(bv, off, 64);
                int   oi = __shfl_xor(bi, off, 64);
                if (better(ov, oi, bv, bi)) { bv = ov; bi = oi; }
            }
            if (lane == 0) topg[p] = bi;
            if (c0i == bi) c0v = -INFINITY;
            if (c1i == bi) c1v = -INFINITY;
            if (c2i == bi) c2v = -INFINITY;
        }
    }
    __syncthreads();
    if (tid < N_) { int g = topg[tid >> 5]; nidx[tid] = nbt[g * G_ + (tid & 31)]; }
    else if (tid < 2 * N_) kills[tid - N_] = 0;
    else if (tid >= 640 && tid < 640 + D_) lcs[tid - 640] = lc[(size_t)row * D_ + (tid - 640)];
    __syncthreads();
    if (tid < 600) {
        int j = tid >> 2, h = tid & 3;
        int d0 = h * 75;
        const float* wp = Wq + (size_t)d0 * DQKV_ + j;
        float acc = 0.f;
        #pragma unroll 5
        for (int dd = 0; dd < 75; ++dd) acc += lcs[d0 + dd] * wp[(size_t)dd * DQKV_];
        acc += __shfl_xor(acc, 1, 64);
        acc += __shfl_xor(acc, 2, 64);
        if (h == 0) qs[j] = acc;
    } else {
        int t0 = tid - 600;
        for (int s = t0; s < 4 * N_; s += 424) {
            int n = s >> 2, cc = s & 3;
            int sidx = nidx[n];
            int clo = cc * 80;
            int lo = (n + 1 > clo) ? n + 1 : clo;
            int hi = clo + 80;
            bool mt = false;
            #pragma unroll 4
            for (int n2 = lo; n2 < hi; ++n2) mt |= (nidx[n2] == sidx);
            if (mt) kills[n] = 1;
        }
    }
    __syncthreads();
    if (tid < 600) {
        int d = tid >> 1, h = tid & 1;
        int j0 = h * 75;
        const float* wrow = Wk + (size_t)d * DQKV_ + j0;
        float acc = 0.f;
        #pragma unroll 5
        for (int jj = 0; jj < 75; ++jj) acc += wrow[jj] * qs[j0 + jj];
        acc += __shfl_xor(acc, 1, 64);
        if (h == 0) qks[d] = acc;
    }
    __syncthreads();
    const float ISC = 0.08164965809277260327f;
    const float4* q4 = (const float4*)qks;
    for (int s = tid; s < 8 * N_; s += NTS) {
        int n = s >> 3, h = s & 7;
        const float4* sc4 = (const float4*)(SC + (size_t)nidx[n] * D_);
        int c0 = h * 9;
        float acc = 0.f;
        #pragma unroll
        for (int cc = 0; cc < 9; ++cc) {
            float4 a = sc4[c0 + cc];
            float4 b = q4[c0 + cc];
            acc += a.x * b.x + a.y * b.y + a.z * b.z + a.w * b.w;
        }
        if (h < 3) {
            float4 a = sc4[72 + h];
            float4 b = q4[72 + h];
            acc += a.x * b.x + a.y * b.y + a.z * b.z + a.w * b.w;
        }
        acc += __shfl_xor(acc, 1, 64);
        acc += __shfl_xor(acc, 2, 64);
        acc += __shfl_xor(acc, 4, 64);
        if (h == 0) lg[n] = acc * ISC;
    }
    __syncthreads();
    float v = (tid < N_) ? lg[tid] : -INFINITY;
    float m = v;
    #pragma unroll
    for (int off = 32; off; off >>= 1) m = fmaxf(m, __shfl_xor(m, off, 64));
    if (lane == 0) redA[wave] = m;
    __syncthreads();
    m = redA[0];
    #pragma unroll
    for (int w = 1; w < NWS; ++w) m = fmaxf(m, redA[w]);
    float e = (tid < N_) ? expf(v - m) : 0.f;
    float ss = e;
    #pragma unroll
    for (int off = 32; off; off >>= 1) ss += __shfl_xor(ss, off, 64);
    if (lane == 0) redB[wave] = ss;
    __syncthreads();
    float tot = redB[0];
    #pragma unroll
    for (int w = 1; w < NWS; ++w) tot += redB[w];
    float lsum = logf(tot);
    if (tid < N_ && !kills[tid]) outrow[nidx[tid]] = (v - m) - lsum;
}

extern "C" void kernel_launch(void* const* d_in, const int* in_sizes, int n_in,
                              void* d_out, int out_size, void* d_ws, size_t ws_size,
                              hipStream_t stream) {
    const float* pred = (const float*)d_in[0];
    const float* lc   = (const float*)d_in[1];
    const float* SC   = (const float*)d_in[2];
    const float* Wq   = (const float*)d_in[3];
    const float* Wk   = (const float*)d_in[4];
    const int*   nbt  = (const int*)d_in[5];
    float* out = (float*)d_out;

    const size_t nKC = (size_t)S_ * KSTR;
    const size_t nQ  = (size_t)T_ * B_ * KSTR;
    const size_t need = (nKC + nQ) * sizeof(float) + (size_t)T_ * B_ * K_ * sizeof(int);
    if (ws_size >= need) {
        float* KC    = (float*)d_ws;
        float* Qws   = KC + nKC;
        int*   wstop = (int*)(Qws + nQ);
        gemm_kernel<<<dim3(NBK3 + NBQ3), dim3(NTG), 0, stream>>>(SC, lc, Wk, Wq, KC, Qws);
        scan_kernel<<<dim3(T_ * B_), dim3(NTS), 0, stream>>>(pred, out, wstop);
        attn_kernel<<<dim3(T_ * B_), dim3(NTA), 0, stream>>>(KC, Qws, nbt, wstop, out);
    } else {
        selfatt_fused<<<dim3(T_ * B_), dim3(NTS), 0, stream>>>(
            pred, lc, SC, Wq, Wk, nbt, out);
    }
}

// Round 12
// 108.728 us; speedup vs baseline: 1.8783x; 1.8783x over previous
//
#include <hip/hip_runtime.h>
#include <math.h>

#define T_ 32
#define B_ 16
#define V_ 30000
#define V4 7500
#define D_ 300
#define DQKV_ 150
#define K_ 10
#define G_ 32
#define N_ 320                // K*G
#define S_ 25000
#define S4 6250
#define NTS 1024              // scan threads
#define NTA 512               // attn threads
#define LCAP 4096             // candidate list capacity (expect ~680 for N(0,1))
#define UTH 0xC0000000u       // u-map(2.0f): accept x >= 2.0

__device__ __forceinline__ unsigned umap(float f) {
    unsigned b = __float_as_uint(f);
    unsigned mask = (unsigned)(((int)b) >> 31);      // 0xFFFFFFFF if negative
    return b ^ (mask | 0x80000000u);                 // ascending uint == ascending float
}
__device__ __forceinline__ bool better_u(unsigned au, int ai, unsigned bu, int bi) {
    return (au > bu) || (au == bu && ai < bi);       // higher val, ties -> lower idx
}

// ===== Kernel 1: fill + threshold-collect + exact top-10 select per row =====
__global__ __launch_bounds__(NTS, 2) void scan_kernel(
    const float* __restrict__ pred, float* __restrict__ out,
    int* __restrict__ wstop)
{
    const int row = blockIdx.x, tid = threadIdx.x;
    const int lane = tid & 63, wave = tid >> 6;
    __shared__ unsigned lu[LCAP];          // 16 KB candidate u-keys
    __shared__ int      li[LCAP];          // 16 KB candidate indices
    __shared__ int      cnt;

    if (tid == 0) cnt = 0;
    __syncthreads();

    // fill output row with log(1e-8)
    const float FILL = -18.420680743952367f;
    {
        float4 f4 = make_float4(FILL, FILL, FILL, FILL);
        float4* o4 = (float4*)(out + (size_t)row * S_);
        #pragma unroll
        for (int k = 0; k < 7; ++k) { int i = tid + k * NTS; if (i < S4) o4[i] = f4; }
    }

    // stream row: collect candidates with x >= 2.0 (u >= UTH); pure streaming
    {
        const float4* p4 = (const float4*)(pred + (size_t)row * V_);
        #pragma unroll
        for (int k = 0; k < 8; ++k) {
            int i = tid + k * NTS;
            if (i < V4) {
                float4 v = p4[i];
                unsigned u0 = umap(v.x), u1 = umap(v.y), u2 = umap(v.z), u3 = umap(v.w);
                int base = i * 4;
                if (u0 >= UTH) { int p = atomicAdd(&cnt, 1); if (p < LCAP) { lu[p] = u0; li[p] = base; } }
                if (u1 >= UTH) { int p = atomicAdd(&cnt, 1); if (p < LCAP) { lu[p] = u1; li[p] = base + 1; } }
                if (u2 >= UTH) { int p = atomicAdd(&cnt, 1); if (p < LCAP) { lu[p] = u2; li[p] = base + 2; } }
                if (u3 >= UTH) { int p = atomicAdd(&cnt, 1); if (p < LCAP) { lu[p] = u3; li[p] = base + 3; } }
            }
        }
    }
    __syncthreads();
    const int c = cnt;

    if (c >= K_ && c <= LCAP) {
        // main path: wave 0 selects exact top-10 from c candidates
        if (wave == 0) {
            for (int p = 0; p < K_; ++p) {
                unsigned bu = 0; int bi = 0x7fffffff;
                for (int s = lane; s < c; s += 64) {
                    unsigned uu = lu[s]; int ii = li[s];
                    if (better_u(uu, ii, bu, bi)) { bu = uu; bi = ii; }
                }
                #pragma unroll
                for (int off = 32; off; off >>= 1) {
                    unsigned ou = __shfl_xor(bu, off, 64);
                    int      oi = __shfl_xor(bi, off, 64);
                    if (better_u(ou, oi, bu, bi)) { bu = ou; bi = oi; }
                }
                if (lane == 0) wstop[row * K_ + p] = bi;
                // remove winner (unique by idx)
                for (int s = lane; s < c; s += 64)
                    if (li[s] == bi && lu[s] == bu) lu[s] = 0;
            }
        }
    } else {
        // exact fallback (never triggers for N(0,1) input): wave 0 re-scans row
        if (wave == 0) {
            unsigned tu[K_]; int tix[K_];
            #pragma unroll
            for (int s = 0; s < K_; ++s) { tu[s] = 0; tix[s] = 0x7fffffff; }
            const float* prow = pred + (size_t)row * V_;
            for (int i = lane; i < V_; i += 64) {
                unsigned u = umap(prow[i]);
                if (better_u(u, i, tu[K_-1], tix[K_-1])) {
                    tu[K_-1] = u; tix[K_-1] = i;
                    #pragma unroll
                    for (int s = K_-1; s > 0; --s)
                        if (better_u(tu[s], tix[s], tu[s-1], tix[s-1])) {
                            unsigned a = tu[s]; tu[s] = tu[s-1]; tu[s-1] = a;
                            int b2 = tix[s]; tix[s] = tix[s-1]; tix[s-1] = b2;
                        }
                }
            }
            for (int p = 0; p < K_; ++p) {
                unsigned bu = tu[0]; int bi = tix[0];
                #pragma unroll
                for (int s = 1; s < K_; ++s)
                    if (better_u(tu[s], tix[s], bu, bi)) { bu = tu[s]; bi = tix[s]; }
                #pragma unroll
                for (int off = 32; off; off >>= 1) {
                    unsigned ou = __shfl_xor(bu, off, 64);
                    int      oi = __shfl_xor(bi, off, 64);
                    if (better_u(ou, oi, bu, bi)) { bu = ou; bi = oi; }
                }
                if (lane == 0) wstop[row * K_ + p] = bi;
                #pragma unroll
                for (int s = 0; s < K_; ++s)
                    if (tix[s] == bi) tu[s] = 0;
            }
        }
    }
}

// == Kernel 2: q=lc@Wq, qk=Wk@q, logits=qk.SC[n], softmax, scatter (no GEMM) ==
__global__ __launch_bounds__(NTA) void attn_kernel(
    const float* __restrict__ lc, const float* __restrict__ SC,
    const float* __restrict__ Wq, const float* __restrict__ Wk,
    const int* __restrict__ nbt, const int* __restrict__ wstop,
    float* __restrict__ out)
{
    const int row = blockIdx.x, tid = threadIdx.x;
    const int lane = tid & 63, wave = tid >> 6;
    __shared__ int   topg[K_];
    __shared__ float lcs[D_];
    __shared__ float qs[DQKV_];
    __shared__ __align__(16) float qks[D_];
    __shared__ int   nidx[N_];
    __shared__ float lg[N_];
    __shared__ int   kills[N_];
    __shared__ float redA[8], redB[8];
    float* outrow = out + (size_t)row * S_;

    // P1: top-10 ids + location-context row + kill flags
    if (tid < K_) topg[tid] = wstop[row * K_ + tid];
    if (tid >= 64 && tid < 64 + D_) lcs[tid - 64] = lc[(size_t)row * D_ + (tid - 64)];
    for (int i = tid; i < N_; i += NTA) kills[i] = 0;
    __syncthreads();                                   // BAR1

    // P2: neighbours  ∥  q[j] = lcs . Wq[:,j]  (600 units, 4 lanes per output)
    if (tid < N_) nidx[tid] = nbt[topg[tid >> 5] * G_ + (tid & 31)];
    for (int t = tid; t < 4 * DQKV_; t += NTA) {
        int j = t >> 2, h = t & 3;
        int d0 = h * 75;
        const float* wp = Wq + (size_t)d0 * DQKV_ + j;
        float acc = 0.f;
        #pragma unroll 5
        for (int dd = 0; dd < 75; ++dd) acc += lcs[d0 + dd] * wp[(size_t)dd * DQKV_];
        acc += __shfl_xor(acc, 1, 64);
        acc += __shfl_xor(acc, 2, 64);
        if (h == 0) qs[j] = acc;
    }
    __syncthreads();                                   // BAR2

    // P3: qk[d] = Wk[d,:] . q  (600 units, 2 lanes per output)
    for (int t = tid; t < 2 * D_; t += NTA) {
        int d = t >> 1, h = t & 1;
        int j0 = h * 75;
        const float* wrow = Wk + (size_t)d * DQKV_ + j0;
        float acc = 0.f;
        #pragma unroll 5
        for (int jj = 0; jj < 75; ++jj) acc += wrow[jj] * qs[j0 + jj];
        acc += __shfl_xor(acc, 1, 64);
        if (h == 0) qks[d] = acc;
    }
    __syncthreads();                                   // BAR3

    // P4: logits[n] = (qk . SC[nidx[n]]) / sqrt(150), 8 lanes/dot, ~10 f4 MLP
    const float ISC = 0.08164965809277260327f;   // 1/sqrt(150)
    const float4* q4 = (const float4*)qks;
    for (int s = tid; s < 8 * N_; s += NTA) {    // 2560 lane-slots, 5 passes
        int n = s >> 3, h = s & 7;
        const float4* sc4 = (const float4*)(SC + (size_t)nidx[n] * D_);
        int c0 = h * 9;
        float acc = 0.f;
        #pragma unroll
        for (int cc = 0; cc < 9; ++cc) {
            float4 a = sc4[c0 + cc];
            float4 b = q4[c0 + cc];
            acc += a.x * b.x + a.y * b.y + a.z * b.z + a.w * b.w;
        }
        if (h < 3) {                              // chunks 72..74
            float4 a = sc4[72 + h];
            float4 b = q4[72 + h];
            acc += a.x * b.x + a.y * b.y + a.z * b.z + a.w * b.w;
        }
        acc += __shfl_xor(acc, 1, 64);
        acc += __shfl_xor(acc, 2, 64);
        acc += __shfl_xor(acc, 4, 64);
        if (h == 0) lg[n] = acc * ISC;
    }
    __syncthreads();                                   // BAR4

    // P5: softmax stats over 320
    float v = (tid < N_) ? lg[tid] : -INFINITY;
    float m = v;
    #pragma unroll
    for (int off = 32; off; off >>= 1) m = fmaxf(m, __shfl_xor(m, off, 64));
    if (lane == 0) redA[wave] = m;
    __syncthreads();                                   // BAR5
    m = redA[0];
    #pragma unroll
    for (int w = 1; w < 8; ++w) m = fmaxf(m, redA[w]);

    float ss = (tid < N_) ? expf(v - m) : 0.f;
    #pragma unroll
    for (int off = 32; off; off >>= 1) ss += __shfl_xor(ss, off, 64);
    if (lane == 0) redB[wave] = ss;
    __syncthreads();                                   // BAR6
    float tot = redB[0];
    #pragma unroll
    for (int w = 1; w < 8; ++w) tot += redB[w];
    float lsum = logf(tot);

    // P6: last-write-wins duplicate detection: 1280 chunk-scans of width 80
    for (int s = tid; s < 4 * N_; s += NTA) {
        int n = s >> 2, cix = s & 3;
        int sidx = nidx[n];
        int clo = cix * 80;
        int lo = (n + 1 > clo) ? n + 1 : clo;
        int hi = clo + 80;
        bool mt = false;
        #pragma unroll 4
        for (int n2 = lo; n2 < hi; ++n2) mt |= (nidx[n2] == sidx);
        if (mt) kills[n] = 1;
    }
    __syncthreads();                                   // BAR7

    // P7: scatter (fill from scan_kernel already in place)
    if (tid < N_ && !kills[tid]) outrow[nidx[tid]] = (v - m) - lsum;
}

// ================= Fallback: fused single kernel (needs no ws) ===============
#define NWS 16
__device__ __forceinline__ bool better(float av, int ai, float bv, int bi) {
    return (av > bv) || (av == bv && ai < bi);
}
__global__ __launch_bounds__(NTS, 4) void selfatt_fused(
    const float* __restrict__ pred, const float* __restrict__ lc,
    const float* __restrict__ SC, const float* __restrict__ Wq,
    const float* __restrict__ Wk, const int* __restrict__ nbt,
    float* __restrict__ out)
{
    const int row = blockIdx.x, tid = threadIdx.x;
    const int lane = tid & 63, wave = tid >> 6;
    __shared__ float wcv[NWS * K_];
    __shared__ int   wci[NWS * K_];
    __shared__ int   topg[K_];
    __shared__ float lcs[D_];
    __shared__ float qs[DQKV_];
    __shared__ __align__(16) float qks[D_];
    __shared__ int   nidx[N_];
    __shared__ float lg[N_];
    __shared__ int   kills[N_];
    __shared__ float redA[NWS], redB[NWS];
    float* outrow = out + (size_t)row * S_;
    const float FILL = -18.420680743952367f;
    {
        float4 f4 = make_float4(FILL, FILL, FILL, FILL);
        float4* o4 = (float4*)outrow;
        #pragma unroll
        for (int k = 0; k < 7; ++k) { int i = tid + k * NTS; if (i < S4) o4[i] = f4; }
    }
    float tv[K_]; int ti[K_];
    #pragma unroll
    for (int s = 0; s < K_; ++s) { tv[s] = -INFINITY; ti[s] = 0x7fffffff; }
    {
        const float4* p4 = (const float4*)(pred + (size_t)row * V_);
        const float4 NEG = make_float4(-INFINITY, -INFINITY, -INFINITY, -INFINITY);
        float4 a[8]; int ib[8];
        #pragma unroll
        for (int u = 0; u < 8; ++u) {
            int i = tid + u * NTS;
            a[u]  = (i < V4) ? p4[i] : NEG;
            ib[u] = (i < V4) ? i * 4 : 0x7ffffff0;
        }
        #pragma unroll
        for (int u = 0; u < 8; ++u) {
            float x = a[u].x, y = a[u].y, z = a[u].z, w = a[u].w;
            float m4 = fmaxf(fmaxf(x, y), fmaxf(z, w));
            if (!(m4 < tv[K_-1])) {
                float vals[4] = {x, y, z, w};
                #pragma unroll
                for (int cc = 0; cc < 4; ++cc) {
                    float val = vals[cc];
                    int   idx = ib[u] + cc;
                    if (better(val, idx, tv[K_-1], ti[K_-1])) {
                        tv[K_-1] = val; ti[K_-1] = idx;
                        #pragma unroll
                        for (int s = K_-1; s > 0; --s) {
                            if (better(tv[s], ti[s], tv[s-1], ti[s-1])) {
                                float fx = tv[s]; tv[s] = tv[s-1]; tv[s-1] = fx;
                                int   iy = ti[s]; ti[s] = ti[s-1]; ti[s-1] = iy;
                            }
                        }
                    }
                }
            }
        }
    }
    for (int p = 0; p < K_; ++p) {
        float bv = tv[0]; int bi = ti[0];
        #pragma unroll
        for (int s = 1; s < K_; ++s)
            if (better(tv[s], ti[s], bv, bi)) { bv = tv[s]; bi = ti[s]; }
        #pragma unroll
        for (int off = 32; off; off >>= 1) {
            float ov = __shfl_xor(bv, off, 64);
            int   oi = __shfl_xor(bi, off, 64);
            if (better(ov, oi, bv, bi)) { bv = ov; bi = oi; }
        }
        if (lane == 0) { wcv[wave * K_ + p] = bv; wci[wave * K_ + p] = bi; }
        #pragma unroll
        for (int s = 0; s < K_; ++s)
            if (ti[s] == bi) tv[s] = -INFINITY;
    }
    __syncthreads();
    if (wave == 0) {
        float c0v = wcv[lane],      c1v = wcv[64 + lane];
        int   c0i = wci[lane],      c1i = wci[64 + lane];
        float c2v = (lane < 32) ? wcv[128 + lane] : -INFINITY;
        int   c2i = (lane < 32) ? wci[128 + lane] : 0x7fffffff;
        for (int p = 0; p < K_; ++p) {
            float bv = c0v; int bi = c0i;
            if (better(c1v, c1i, bv, bi)) { bv = c1v; bi = c1i; }
            if (better(c2v, c2i, bv, bi)) { bv = c2v; bi = c2i; }
            #pragma unroll
            for (int off = 32; off; off >>= 1) {
                float ov = __shfl_xor(bv, off, 64);
                int   oi = __shfl_xor(bi, off, 64);
                if (better(ov, oi, bv, bi)) { bv = ov; bi = oi; }
            }
            if (lane == 0) topg[p] = bi;
            if (c0i == bi) c0v = -INFINITY;
            if (c1i == bi) c1v = -INFINITY;
            if (c2i == bi) c2v = -INFINITY;
        }
    }
    __syncthreads();
    if (tid < N_) { int g = topg[tid >> 5]; nidx[tid] = nbt[g * G_ + (tid & 31)]; }
    else if (tid < 2 * N_) kills[tid - N_] = 0;
    else if (tid >= 640 && tid < 640 + D_) lcs[tid - 640] = lc[(size_t)row * D_ + (tid - 640)];
    __syncthreads();
    if (tid < 600) {
        int j = tid >> 2, h = tid & 3;
        int d0 = h * 75;
        const float* wp = Wq + (size_t)d0 * DQKV_ + j;
        float acc = 0.f;
        #pragma unroll 5
        for (int dd = 0; dd < 75; ++dd) acc += lcs[d0 + dd] * wp[(size_t)dd * DQKV_];
        acc += __shfl_xor(acc, 1, 64);
        acc += __shfl_xor(acc, 2, 64);
        if (h == 0) qs[j] = acc;
    } else {
        int t0 = tid - 600;
        for (int s = t0; s < 4 * N_; s += 424) {
            int n = s >> 2, cc = s & 3;
            int sidx = nidx[n];
            int clo = cc * 80;
            int lo = (n + 1 > clo) ? n + 1 : clo;
            int hi = clo + 80;
            bool mt = false;
            #pragma unroll 4
            for (int n2 = lo; n2 < hi; ++n2) mt |= (nidx[n2] == sidx);
            if (mt) kills[n] = 1;
        }
    }
    __syncthreads();
    if (tid < 600) {
        int d = tid >> 1, h = tid & 1;
        int j0 = h * 75;
        const float* wrow = Wk + (size_t)d * DQKV_ + j0;
        float acc = 0.f;
        #pragma unroll 5
        for (int jj = 0; jj < 75; ++jj) acc += wrow[jj] * qs[j0 + jj];
        acc += __shfl_xor(acc, 1, 64);
        if (h == 0) qks[d] = acc;
    }
    __syncthreads();
    const float ISC = 0.08164965809277260327f;
    const float4* q4 = (const float4*)qks;
    for (int s = tid; s < 8 * N_; s += NTS) {
        int n = s >> 3, h = s & 7;
        const float4* sc4 = (const float4*)(SC + (size_t)nidx[n] * D_);
        int c0 = h * 9;
        float acc = 0.f;
        #pragma unroll
        for (int cc = 0; cc < 9; ++cc) {
            float4 a = sc4[c0 + cc];
            float4 b = q4[c0 + cc];
            acc += a.x * b.x + a.y * b.y + a.z * b.z + a.w * b.w;
        }
        if (h < 3) {
            float4 a = sc4[72 + h];
            float4 b = q4[72 + h];
            acc += a.x * b.x + a.y * b.y + a.z * b.z + a.w * b.w;
        }
        acc += __shfl_xor(acc, 1, 64);
        acc += __shfl_xor(acc, 2, 64);
        acc += __shfl_xor(acc, 4, 64);
        if (h == 0) lg[n] = acc * ISC;
    }
    __syncthreads();
    float v = (tid < N_) ? lg[tid] : -INFINITY;
    float m = v;
    #pragma unroll
    for (int off = 32; off; off >>= 1) m = fmaxf(m, __shfl_xor(m, off, 64));
    if (lane == 0) redA[wave] = m;
    __syncthreads();
    m = redA[0];
    #pragma unroll
    for (int w = 1; w < NWS; ++w) m = fmaxf(m, redA[w]);
    float e = (tid < N_) ? expf(v - m) : 0.f;
    float ss = e;
    #pragma unroll
    for (int off = 32; off; off >>= 1) ss += __shfl_xor(ss, off, 64);
    if (lane == 0) redB[wave] = ss;
    __syncthreads();
    float tot = redB[0];
    #pragma unroll
    for (int w = 1; w < NWS; ++w) tot += redB[w];
    float lsum = logf(tot);
    if (tid < N_ && !kills[tid]) outrow[nidx[tid]] = (v - m) - lsum;
}

extern "C" void kernel_launch(void* const* d_in, const int* in_sizes, int n_in,
                              void* d_out, int out_size, void* d_ws, size_t ws_size,
                              hipStream_t stream) {
    const float* pred = (const float*)d_in[0];
    const float* lc   = (const float*)d_in[1];
    const float* SC   = (const float*)d_in[2];
    const float* Wq   = (const float*)d_in[3];
    const float* Wk   = (const float*)d_in[4];
    const int*   nbt  = (const int*)d_in[5];
    float* out = (float*)d_out;

    const size_t need = (size_t)T_ * B_ * K_ * sizeof(int);
    if (ws_size >= need) {
        int* wstop = (int*)d_ws;
        scan_kernel<<<dim3(T_ * B_), dim3(NTS), 0, stream>>>(pred, out, wstop);
        attn_kernel<<<dim3(T_ * B_), dim3(NTA), 0, stream>>>(
            lc, SC, Wq, Wk, nbt, wstop, out);
    } else {
        selfatt_fused<<<dim3(T_ * B_), dim3(NTS), 0, stream>>>(
            pred, lc, SC, Wq, Wk, nbt, out);
    }
}

// Round 13
// 103.460 us; speedup vs baseline: 1.9740x; 1.0509x over previous
//
#include <hip/hip_runtime.h>
#include <math.h>

#define T_ 32
#define B_ 16
#define V_ 30000
#define V4 7500
#define D_ 300
#define DQKV_ 150
#define K_ 10
#define G_ 32
#define N_ 320                // K*G
#define S_ 25000
#define S4 6250
#define NTS 1024              // scan threads
#define NTA 512               // attn threads
#define LCAP 4096             // candidate list capacity (expect ~680 for N(0,1))
#define UTH 0xC0000000u       // u-map(2.0f): accept x >= 2.0

__device__ __forceinline__ unsigned umap(float f) {
    unsigned b = __float_as_uint(f);
    unsigned mask = (unsigned)(((int)b) >> 31);      // 0xFFFFFFFF if negative
    return b ^ (mask | 0x80000000u);                 // ascending uint == ascending float
}
__device__ __forceinline__ bool better_u(unsigned au, int ai, unsigned bu, int bi) {
    return (au > bu) || (au == bu && ai < bi);       // higher val, ties -> lower idx
}

// ===== Kernel 1: fill + threshold-collect + exact top-10 select per row =====
__global__ __launch_bounds__(NTS, 2) void scan_kernel(
    const float* __restrict__ pred, float* __restrict__ out,
    int* __restrict__ wstop)
{
    const int row = blockIdx.x, tid = threadIdx.x;
    const int lane = tid & 63, wave = tid >> 6;
    __shared__ unsigned lu[LCAP];          // 16 KB candidate u-keys
    __shared__ int      li[LCAP];          // 16 KB candidate indices
    __shared__ int      cnt;

    if (tid == 0) cnt = 0;
    __syncthreads();

    // fill output row with log(1e-8)
    const float FILL = -18.420680743952367f;
    {
        float4 f4 = make_float4(FILL, FILL, FILL, FILL);
        float4* o4 = (float4*)(out + (size_t)row * S_);
        #pragma unroll
        for (int k = 0; k < 7; ++k) { int i = tid + k * NTS; if (i < S4) o4[i] = f4; }
    }

    // stream row: collect candidates with x >= 2.0 (u >= UTH); pure streaming
    {
        const float4* p4 = (const float4*)(pred + (size_t)row * V_);
        #pragma unroll
        for (int k = 0; k < 8; ++k) {
            int i = tid + k * NTS;
            if (i < V4) {
                float4 v = p4[i];
                unsigned u0 = umap(v.x), u1 = umap(v.y), u2 = umap(v.z), u3 = umap(v.w);
                int base = i * 4;
                if (u0 >= UTH) { int p = atomicAdd(&cnt, 1); if (p < LCAP) { lu[p] = u0; li[p] = base; } }
                if (u1 >= UTH) { int p = atomicAdd(&cnt, 1); if (p < LCAP) { lu[p] = u1; li[p] = base + 1; } }
                if (u2 >= UTH) { int p = atomicAdd(&cnt, 1); if (p < LCAP) { lu[p] = u2; li[p] = base + 2; } }
                if (u3 >= UTH) { int p = atomicAdd(&cnt, 1); if (p < LCAP) { lu[p] = u3; li[p] = base + 3; } }
            }
        }
    }
    __syncthreads();
    const int c = cnt;

    if (c >= K_ && c <= LCAP) {
        // main path: wave 0 selects exact top-10 from c candidates
        if (wave == 0) {
            for (int p = 0; p < K_; ++p) {
                unsigned bu = 0; int bi = 0x7fffffff;
                for (int s = lane; s < c; s += 64) {
                    unsigned uu = lu[s]; int ii = li[s];
                    if (better_u(uu, ii, bu, bi)) { bu = uu; bi = ii; }
                }
                #pragma unroll
                for (int off = 32; off; off >>= 1) {
                    unsigned ou = __shfl_xor(bu, off, 64);
                    int      oi = __shfl_xor(bi, off, 64);
                    if (better_u(ou, oi, bu, bi)) { bu = ou; bi = oi; }
                }
                if (lane == 0) wstop[row * K_ + p] = bi;
                // remove winner (unique by idx)
                for (int s = lane; s < c; s += 64)
                    if (li[s] == bi && lu[s] == bu) lu[s] = 0;
            }
        }
    } else {
        // exact fallback (never triggers for N(0,1) input): wave 0 re-scans row
        if (wave == 0) {
            unsigned tu[K_]; int tix[K_];
            #pragma unroll
            for (int s = 0; s < K_; ++s) { tu[s] = 0; tix[s] = 0x7fffffff; }
            const float* prow = pred + (size_t)row * V_;
            for (int i = lane; i < V_; i += 64) {
                unsigned u = umap(prow[i]);
                if (better_u(u, i, tu[K_-1], tix[K_-1])) {
                    tu[K_-1] = u; tix[K_-1] = i;
                    #pragma unroll
                    for (int s = K_-1; s > 0; --s)
                        if (better_u(tu[s], tix[s], tu[s-1], tix[s-1])) {
                            unsigned a = tu[s]; tu[s] = tu[s-1]; tu[s-1] = a;
                            int b2 = tix[s]; tix[s] = tix[s-1]; tix[s-1] = b2;
                        }
                }
            }
            for (int p = 0; p < K_; ++p) {
                unsigned bu = tu[0]; int bi = tix[0];
                #pragma unroll
                for (int s = 1; s < K_; ++s)
                    if (better_u(tu[s], tix[s], bu, bi)) { bu = tu[s]; bi = tix[s]; }
                #pragma unroll
                for (int off = 32; off; off >>= 1) {
                    unsigned ou = __shfl_xor(bu, off, 64);
                    int      oi = __shfl_xor(bi, off, 64);
                    if (better_u(ou, oi, bu, bi)) { bu = ou; bi = oi; }
                }
                if (lane == 0) wstop[row * K_ + p] = bi;
                #pragma unroll
                for (int s = 0; s < K_; ++s)
                    if (tix[s] == bi) tu[s] = 0;
            }
        }
    }
}

// == Kernel 2: q=lc@Wq, qk=Wk@q (coalesced), logits, softmax, scatter =========
__global__ __launch_bounds__(NTA) void attn_kernel(
    const float* __restrict__ lc, const float* __restrict__ SC,
    const float* __restrict__ Wq, const float* __restrict__ Wk,
    const int* __restrict__ nbt, const int* __restrict__ wstop,
    float* __restrict__ out)
{
    const int row = blockIdx.x, tid = threadIdx.x;
    const int lane = tid & 63, wave = tid >> 6;
    __shared__ int   topg[K_];
    __shared__ __align__(16) float lcs[D_];
    __shared__ float qpart[2][DQKV_];
    __shared__ __align__(16) float qks[D_];
    __shared__ int   nidx[N_];
    __shared__ float lg[N_];
    __shared__ int   kills[N_];
    __shared__ float redA[8], redB[8];
    float* outrow = out + (size_t)row * S_;

    // P1: top-10 ids + location-context row (float4) + kill flags
    if (tid < K_) topg[tid] = wstop[row * K_ + tid];
    if (tid >= 64 && tid < 64 + D_ / 4)               // 75 threads, float4
        ((float4*)lcs)[tid - 64] = ((const float4*)(lc + (size_t)row * D_))[tid - 64];
    for (int i = tid; i < N_; i += NTA) kills[i] = 0;
    __syncthreads();                                   // BAR1

    // P2: neighbours ∥ q-partials: unit t=(h*150+j), lanes->consecutive j
    //     (each Wq load instruction reads a contiguous row segment: coalesced)
    if (tid < N_) nidx[tid] = nbt[topg[tid >> 5] * G_ + (tid & 31)];
    if (tid < 2 * DQKV_) {                            // 300 units
        int h = tid / DQKV_;                          // d-half
        int j = tid - h * DQKV_;
        int d0 = h * 150;
        const float* wp = Wq + (size_t)d0 * DQKV_ + j;
        float acc = 0.f;
        #pragma unroll 10
        for (int dd = 0; dd < 150; ++dd)
            acc += lcs[d0 + dd] * wp[(size_t)dd * DQKV_];
        qpart[h][j] = acc;
    }
    __syncthreads();                                   // BAR2

    // P3: qk[d] = Wk[d,:] . q — wave per d-row, lanes split j (coalesced),
    //     shfl-reduce. q hoisted into 3 regs per lane.
    {
        float qv0 = qpart[0][lane] + qpart[1][lane];
        float qv1 = qpart[0][64 + lane] + qpart[1][64 + lane];
        float qv2 = (lane < 22) ? (qpart[0][128 + lane] + qpart[1][128 + lane]) : 0.f;
        #pragma unroll 2
        for (int d = wave; d < D_; d += 8) {
            const float* wr = Wk + (size_t)d * DQKV_;
            float w0 = wr[lane];                      // coalesced 64 floats
            float w1 = wr[64 + lane];                 // coalesced 64 floats
            float w2 = (lane < 22) ? wr[128 + lane] : 0.f;
            float p = w0 * qv0 + w1 * qv1 + w2 * qv2;
            #pragma unroll
            for (int off = 32; off; off >>= 1) p += __shfl_xor(p, off, 64);
            if (lane == 0) qks[d] = p;
        }
    }
    __syncthreads();                                   // BAR3

    // P4: logits[n] = (qk . SC[nidx[n]]) / sqrt(150), 8 lanes/dot, ~10 f4 MLP
    const float ISC = 0.08164965809277260327f;   // 1/sqrt(150)
    const float4* q4 = (const float4*)qks;
    for (int s = tid; s < 8 * N_; s += NTA) {    // 2560 lane-slots, 5 passes
        int n = s >> 3, h = s & 7;
        const float4* sc4 = (const float4*)(SC + (size_t)nidx[n] * D_);
        int c0 = h * 9;
        float acc = 0.f;
        #pragma unroll
        for (int cc = 0; cc < 9; ++cc) {
            float4 a = sc4[c0 + cc];
            float4 b = q4[c0 + cc];
            acc += a.x * b.x + a.y * b.y + a.z * b.z + a.w * b.w;
        }
        if (h < 3) {                              // chunks 72..74
            float4 a = sc4[72 + h];
            float4 b = q4[72 + h];
            acc += a.x * b.x + a.y * b.y + a.z * b.z + a.w * b.w;
        }
        acc += __shfl_xor(acc, 1, 64);
        acc += __shfl_xor(acc, 2, 64);
        acc += __shfl_xor(acc, 4, 64);
        if (h == 0) lg[n] = acc * ISC;
    }
    __syncthreads();                                   // BAR4

    // P5: softmax stats over 320
    float v = (tid < N_) ? lg[tid] : -INFINITY;
    float m = v;
    #pragma unroll
    for (int off = 32; off; off >>= 1) m = fmaxf(m, __shfl_xor(m, off, 64));
    if (lane == 0) redA[wave] = m;
    __syncthreads();                                   // BAR5
    m = redA[0];
    #pragma unroll
    for (int w = 1; w < 8; ++w) m = fmaxf(m, redA[w]);

    float ss = (tid < N_) ? expf(v - m) : 0.f;
    #pragma unroll
    for (int off = 32; off; off >>= 1) ss += __shfl_xor(ss, off, 64);
    if (lane == 0) redB[wave] = ss;
    __syncthreads();                                   // BAR6
    float tot = redB[0];
    #pragma unroll
    for (int w = 1; w < 8; ++w) tot += redB[w];
    float lsum = logf(tot);

    // P6: last-write-wins duplicate detection: 1280 chunk-scans of width 80
    for (int s = tid; s < 4 * N_; s += NTA) {
        int n = s >> 2, cix = s & 3;
        int sidx = nidx[n];
        int clo = cix * 80;
        int lo = (n + 1 > clo) ? n + 1 : clo;
        int hi = clo + 80;
        bool mt = false;
        #pragma unroll 4
        for (int n2 = lo; n2 < hi; ++n2) mt |= (nidx[n2] == sidx);
        if (mt) kills[n] = 1;
    }
    __syncthreads();                                   // BAR7

    // P7: scatter (fill from scan_kernel already in place)
    if (tid < N_ && !kills[tid]) outrow[nidx[tid]] = (v - m) - lsum;
}

// ================= Fallback: fused single kernel (needs no ws) ===============
#define NWS 16
__device__ __forceinline__ bool better(float av, int ai, float bv, int bi) {
    return (av > bv) || (av == bv && ai < bi);
}
__global__ __launch_bounds__(NTS, 4) void selfatt_fused(
    const float* __restrict__ pred, const float* __restrict__ lc,
    const float* __restrict__ SC, const float* __restrict__ Wq,
    const float* __restrict__ Wk, const int* __restrict__ nbt,
    float* __restrict__ out)
{
    const int row = blockIdx.x, tid = threadIdx.x;
    const int lane = tid & 63, wave = tid >> 6;
    __shared__ float wcv[NWS * K_];
    __shared__ int   wci[NWS * K_];
    __shared__ int   topg[K_];
    __shared__ float lcs[D_];
    __shared__ float qs[DQKV_];
    __shared__ __align__(16) float qks[D_];
    __shared__ int   nidx[N_];
    __shared__ float lg[N_];
    __shared__ int   kills[N_];
    __shared__ float redA[NWS], redB[NWS];
    float* outrow = out + (size_t)row * S_;
    const float FILL = -18.420680743952367f;
    {
        float4 f4 = make_float4(FILL, FILL, FILL, FILL);
        float4* o4 = (float4*)outrow;
        #pragma unroll
        for (int k = 0; k < 7; ++k) { int i = tid + k * NTS; if (i < S4) o4[i] = f4; }
    }
    float tv[K_]; int ti[K_];
    #pragma unroll
    for (int s = 0; s < K_; ++s) { tv[s] = -INFINITY; ti[s] = 0x7fffffff; }
    {
        const float4* p4 = (const float4*)(pred + (size_t)row * V_);
        const float4 NEG = make_float4(-INFINITY, -INFINITY, -INFINITY, -INFINITY);
        float4 a[8]; int ib[8];
        #pragma unroll
        for (int u = 0; u < 8; ++u) {
            int i = tid + u * NTS;
            a[u]  = (i < V4) ? p4[i] : NEG;
            ib[u] = (i < V4) ? i * 4 : 0x7ffffff0;
        }
        #pragma unroll
        for (int u = 0; u < 8; ++u) {
            float x = a[u].x, y = a[u].y, z = a[u].z, w = a[u].w;
            float m4 = fmaxf(fmaxf(x, y), fmaxf(z, w));
            if (!(m4 < tv[K_-1])) {
                float vals[4] = {x, y, z, w};
                #pragma unroll
                for (int cc = 0; cc < 4; ++cc) {
                    float val = vals[cc];
                    int   idx = ib[u] + cc;
                    if (better(val, idx, tv[K_-1], ti[K_-1])) {
                        tv[K_-1] = val; ti[K_-1] = idx;
                        #pragma unroll
                        for (int s = K_-1; s > 0; --s) {
                            if (better(tv[s], ti[s], tv[s-1], ti[s-1])) {
                                float fx = tv[s]; tv[s] = tv[s-1]; tv[s-1] = fx;
                                int   iy = ti[s]; ti[s] = ti[s-1]; ti[s-1] = iy;
                            }
                        }
                    }
                }
            }
        }
    }
    for (int p = 0; p < K_; ++p) {
        float bv = tv[0]; int bi = ti[0];
        #pragma unroll
        for (int s = 1; s < K_; ++s)
            if (better(tv[s], ti[s], bv, bi)) { bv = tv[s]; bi = ti[s]; }
        #pragma unroll
        for (int off = 32; off; off >>= 1) {
            float ov = __shfl_xor(bv, off, 64);
            int   oi = __shfl_xor(bi, off, 64);
            if (better(ov, oi, bv, bi)) { bv = ov; bi = oi; }
        }
        if (lane == 0) { wcv[wave * K_ + p] = bv; wci[wave * K_ + p] = bi; }
        #pragma unroll
        for (int s = 0; s < K_; ++s)
            if (ti[s] == bi) tv[s] = -INFINITY;
    }
    __syncthreads();
    if (wave == 0) {
        float c0v = wcv[lane],      c1v = wcv[64 + lane];
        int   c0i = wci[lane],      c1i = wci[64 + lane];
        float c2v = (lane < 32) ? wcv[128 + lane] : -INFINITY;
        int   c2i = (lane < 32) ? wci[128 + lane] : 0x7fffffff;
        for (int p = 0; p < K_; ++p) {
            float bv = c0v; int bi = c0i;
            if (better(c1v, c1i, bv, bi)) { bv = c1v; bi = c1i; }
            if (better(c2v, c2i, bv, bi)) { bv = c2v; bi = c2i; }
            #pragma unroll
            for (int off = 32; off; off >>= 1) {
                float ov = __shfl_xor(bv, off, 64);
                int   oi = __shfl_xor(bi, off, 64);
                if (better(ov, oi, bv, bi)) { bv = ov; bi = oi; }
            }
            if (lane == 0) topg[p] = bi;
            if (c0i == bi) c0v = -INFINITY;
            if (c1i == bi) c1v = -INFINITY;
            if (c2i == bi) c2v = -INFINITY;
        }
    }
    __syncthreads();
    if (tid < N_) { int g = topg[tid >> 5]; nidx[tid] = nbt[g * G_ + (tid & 31)]; }
    else if (tid < 2 * N_) kills[tid - N_] = 0;
    else if (tid >= 640 && tid < 640 + D_) lcs[tid - 640] = lc[(size_t)row * D_ + (tid - 640)];
    __syncthreads();
    if (tid < 600) {
        int j = tid >> 2, h = tid & 3;
        int d0 = h * 75;
        const float* wp = Wq + (size_t)d0 * DQKV_ + j;
        float acc = 0.f;
        #pragma unroll 5
        for (int dd = 0; dd < 75; ++dd) acc += lcs[d0 + dd] * wp[(size_t)dd * DQKV_];
        acc += __shfl_xor(acc, 1, 64);
        acc += __shfl_xor(acc, 2, 64);
        if (h == 0) qs[j] = acc;
    } else {
        int t0 = tid - 600;
        for (int s = t0; s < 4 * N_; s += 424) {
            int n = s >> 2, cc = s & 3;
            int sidx = nidx[n];
            int clo = cc * 80;
            int lo = (n + 1 > clo) ? n + 1 : clo;
            int hi = clo + 80;
            bool mt = false;
            #pragma unroll 4
            for (int n2 = lo; n2 < hi; ++n2) mt |= (nidx[n2] == sidx);
            if (mt) kills[n] = 1;
        }
    }
    __syncthreads();
    if (tid < 600) {
        int d = tid >> 1, h = tid & 1;
        int j0 = h * 75;
        const float* wrow = Wk + (size_t)d * DQKV_ + j0;
        float acc = 0.f;
        #pragma unroll 5
        for (int jj = 0; jj < 75; ++jj) acc += wrow[jj] * qs[j0 + jj];
        acc += __shfl_xor(acc, 1, 64);
        if (h == 0) qks[d] = acc;
    }
    __syncthreads();
    const float ISC = 0.08164965809277260327f;
    const float4* q4 = (const float4*)qks;
    for (int s = tid; s < 8 * N_; s += NTS) {
        int n = s >> 3, h = s & 7;
        const float4* sc4 = (const float4*)(SC + (size_t)nidx[n] * D_);
        int c0 = h * 9;
        float acc = 0.f;
        #pragma unroll
        for (int cc = 0; cc < 9; ++cc) {
            float4 a = sc4[c0 + cc];
            float4 b = q4[c0 + cc];
            acc += a.x * b.x + a.y * b.y + a.z * b.z + a.w * b.w;
        }
        if (h < 3) {
            float4 a = sc4[72 + h];
            float4 b = q4[72 + h];
            acc += a.x * b.x + a.y * b.y + a.z * b.z + a.w * b.w;
        }
        acc += __shfl_xor(acc, 1, 64);
        acc += __shfl_xor(acc, 2, 64);
        acc += __shfl_xor(acc, 4, 64);
        if (h == 0) lg[n] = acc * ISC;
    }
    __syncthreads();
    float v = (tid < N_) ? lg[tid] : -INFINITY;
    float m = v;
    #pragma unroll
    for (int off = 32; off; off >>= 1) m = fmaxf(m, __shfl_xor(m, off, 64));
    if (lane == 0) redA[wave] = m;
    __syncthreads();
    m = redA[0];
    #pragma unroll
    for (int w = 1; w < NWS; ++w) m = fmaxf(m, redA[w]);
    float e = (tid < N_) ? expf(v - m) : 0.f;
    float ss = e;
    #pragma unroll
    for (int off = 32; off; off >>= 1) ss += __shfl_xor(ss, off, 64);
    if (lane == 0) redB[wave] = ss;
    __syncthreads();
    float tot = redB[0];
    #pragma unroll
    for (int w = 1; w < NWS; ++w) tot += redB[w];
    float lsum = logf(tot);
    if (tid < N_ && !kills[tid]) outrow[nidx[tid]] = (v - m) - lsum;
}

extern "C" void kernel_launch(void* const* d_in, const int* in_sizes, int n_in,
                              void* d_out, int out_size, void* d_ws, size_t ws_size,
                              hipStream_t stream) {
    const float* pred = (const float*)d_in[0];
    const float* lc   = (const float*)d_in[1];
    const float* SC   = (const float*)d_in[2];
    const float* Wq   = (const float*)d_in[3];
    const float* Wk   = (const float*)d_in[4];
    const int*   nbt  = (const int*)d_in[5];
    float* out = (float*)d_out;

    const size_t need = (size_t)T_ * B_ * K_ * sizeof(int);
    if (ws_size >= need) {
        int* wstop = (int*)d_ws;
        scan_kernel<<<dim3(T_ * B_), dim3(NTS), 0, stream>>>(pred, out, wstop);
        attn_kernel<<<dim3(T_ * B_), dim3(NTA), 0, stream>>>(
            lc, SC, Wq, Wk, nbt, wstop, out);
    } else {
        selfatt_fused<<<dim3(T_ * B_), dim3(NTS), 0, stream>>>(
            pred, lc, SC, Wq, Wk, nbt, out);
    }
}